// Round 2
// baseline (4587.918 us; speedup 1.0000x reference)
//
#include <hip/hip_runtime.h>
#include <stdint.h>

// ---- problem constants ----
#define TT 1024
#define EE 1024
#define HHD 16
#define HSZ 64
#define LLY 8
#define BBS 4
#define FFD 4096
#define VVC 32000
#define NNR 4096  // B*T

typedef unsigned short u16;
typedef __attribute__((ext_vector_type(8))) short short8;
typedef __attribute__((ext_vector_type(4))) float f32x4;

#define GLD16(g, l)                                                      \
  __builtin_amdgcn_global_load_lds(                                      \
      (const __attribute__((address_space(1))) void*)(g),                \
      (__attribute__((address_space(3))) void*)(l), 16, 0, 0)

__device__ __forceinline__ u16 f2bf(float f) {
  union { float f; unsigned u; } v; v.f = f;
  unsigned r = v.u + 0x7fffu + ((v.u >> 16) & 1u);
  return (u16)(r >> 16);
}

// ---------------- weight transpose + f32->bf16 ----------------
// in: [K][N] f32 -> out: [N][K] bf16
__global__ __launch_bounds__(256) void transpose_cvt(
    const float* __restrict__ in, u16* __restrict__ out, int K, int N) {
  __shared__ float tile[32][33];
  const float* src = in;
  u16* dst = out;
  const int n0 = blockIdx.x * 32, k0 = blockIdx.y * 32;
  const int tx = threadIdx.x & 31, ty = threadIdx.x >> 5;
#pragma unroll
  for (int r = ty; r < 32; r += 8)
    tile[r][tx] = src[(size_t)(k0 + r) * N + n0 + tx];
  __syncthreads();
#pragma unroll
  for (int r = ty; r < 32; r += 8)
    dst[(size_t)(n0 + r) * K + k0 + tx] = f2bf(tile[tx][r]);
}

// ---------------- embedding ----------------
__global__ __launch_bounds__(256) void embed_kernel(
    const int* __restrict__ idx, const float* __restrict__ tok,
    const float* __restrict__ pos, float* __restrict__ x) {
  const int n = blockIdx.x, t = n & (TT - 1);
  const int tok_id = idx[n];
  const float4 a = ((const float4*)(tok + (size_t)tok_id * EE))[threadIdx.x];
  const float4 p = ((const float4*)(pos + (size_t)t * EE))[threadIdx.x];
  float4 r; r.x = a.x + p.x; r.y = a.y + p.y; r.z = a.z + p.z; r.w = a.w + p.w;
  ((float4*)(x + (size_t)n * EE))[threadIdx.x] = r;
}

// ---------------- layernorm (f32 in -> bf16 out) ----------------
__global__ __launch_bounds__(256) void ln_bf16(
    const float* __restrict__ x, const float* __restrict__ g,
    const float* __restrict__ bb, u16* __restrict__ out) {
  const int n = blockIdx.x, tid = threadIdx.x;
  const int lane = tid & 63, w = tid >> 6;
  const float4 v = ((const float4*)(x + (size_t)n * EE))[tid];
  float s = v.x + v.y + v.z + v.w;
  float ss = v.x * v.x + v.y * v.y + v.z * v.z + v.w * v.w;
#pragma unroll
  for (int off = 1; off < 64; off <<= 1) {
    s += __shfl_xor(s, off);
    ss += __shfl_xor(ss, off);
  }
  __shared__ float rs[4], rss[4];
  if (lane == 0) { rs[w] = s; rss[w] = ss; }
  __syncthreads();
  const float S = rs[0] + rs[1] + rs[2] + rs[3];
  const float SS = rss[0] + rss[1] + rss[2] + rss[3];
  const float mean = S * (1.f / 1024.f);
  const float var = SS * (1.f / 1024.f) - mean * mean;
  const float rstd = rsqrtf(fmaxf(var, 0.f) + 1e-5f);
  const float4 gv = ((const float4*)g)[tid];
  const float4 bv = ((const float4*)bb)[tid];
  u16 r0 = f2bf((v.x - mean) * rstd * gv.x + bv.x);
  u16 r1 = f2bf((v.y - mean) * rstd * gv.y + bv.y);
  u16 r2 = f2bf((v.z - mean) * rstd * gv.z + bv.z);
  u16 r3 = f2bf((v.w - mean) * rstd * gv.w + bv.w);
  uint2 pk; pk.x = (unsigned)r0 | ((unsigned)r1 << 16);
  pk.y = (unsigned)r2 | ((unsigned)r3 << 16);
  *(uint2*)(out + (size_t)n * EE + tid * 4) = pk;
}

// ---------------- GEMM: A[M][K] bf16 x Bt[N][K] bf16 ----------------
enum { EPI_BF16 = 0, EPI_BIAS_RELU = 1, EPI_QKV = 2, EPI_VT = 3, EPI_RES = 4, EPI_LOGITS = 5 };

template <int EPI>
__global__ __launch_bounds__(256) void gemm_bf16(
    const u16* __restrict__ A, const u16* __restrict__ Bt,
    const float* __restrict__ bias, void* __restrict__ out,
    float* __restrict__ xres, int M, int N, int K) {
  __shared__ u16 As[128][32];
  __shared__ u16 Bs[128][32];
  const int tid = threadIdx.x;
  const int lane = tid & 63, wid = tid >> 6;
  const int wm = wid >> 1, wn = wid & 1;
  const size_t m0 = (size_t)blockIdx.y * 128, n0 = (size_t)blockIdx.x * 128;

  f32x4 acc[4][4] = {};

  const int arow = lane >> 2;        // 0..15 within 16-row group
  const int acol = (lane & 3) * 8;   // 0,8,16,24
  const u16* agp0 = A + (m0 + (size_t)(wid * 32 + arow)) * K + acol;
  const u16* agp1 = agp0 + (size_t)16 * K;
  const u16* bgp0 = Bt + (n0 + (size_t)(wid * 32 + arow)) * K + acol;
  const u16* bgp1 = bgp0 + (size_t)16 * K;

  const int fr = lane & 15, fc = (lane >> 4) * 8;

  for (int k0 = 0; k0 < K; k0 += 32) {
    __syncthreads();
    GLD16(agp0 + k0, &As[wid * 32][0]);
    GLD16(agp1 + k0, &As[wid * 32 + 16][0]);
    GLD16(bgp0 + k0, &Bs[wid * 32][0]);
    GLD16(bgp1 + k0, &Bs[wid * 32 + 16][0]);
    asm volatile("s_waitcnt vmcnt(0)" ::: "memory");
    __syncthreads();
    short8 af[4], bf[4];
#pragma unroll
    for (int m = 0; m < 4; ++m)
      af[m] = *(const short8*)&As[wm * 64 + m * 16 + fr][fc];
#pragma unroll
    for (int n = 0; n < 4; ++n)
      bf[n] = *(const short8*)&Bs[wn * 64 + n * 16 + fr][fc];
#pragma unroll
    for (int m = 0; m < 4; ++m)
#pragma unroll
      for (int n = 0; n < 4; ++n)
        acc[m][n] = __builtin_amdgcn_mfma_f32_16x16x32_bf16(af[m], bf[n], acc[m][n], 0, 0, 0);
  }

  const int fg = (lane >> 4) * 4;
#pragma unroll
  for (int m = 0; m < 4; ++m) {
#pragma unroll
    for (int n = 0; n < 4; ++n) {
      const size_t col = n0 + wn * 64 + n * 16 + fr;
      float bv = 0.f;
      if (EPI == EPI_BIAS_RELU || EPI == EPI_RES || EPI == EPI_LOGITS) bv = bias[col];
#pragma unroll
      for (int f = 0; f < 4; ++f) {
        const size_t row = m0 + wm * 64 + m * 16 + fg + f;
        const float v = acc[m][n][f];
        if (EPI == EPI_BF16) {
          ((u16*)out)[row * N + col] = f2bf(v);
        } else if (EPI == EPI_BIAS_RELU) {
          ((u16*)out)[row * N + col] = f2bf(fmaxf(v + bv, 0.f));
        } else if (EPI == EPI_QKV) {
          const size_t b = row >> 10, t = row & 1023, hh = col >> 6, hs = col & 63;
          ((u16*)out)[((b * HHD + hh) * TT + t) * HSZ + hs] = f2bf(v);
        } else if (EPI == EPI_VT) {
          const size_t b = row >> 10, t = row & 1023, hh = col >> 6, hs = col & 63;
          ((u16*)out)[((b * HHD + hh) * HSZ + hs) * TT + t] = f2bf(v);
        } else if (EPI == EPI_RES) {
          xres[row * N + col] += v + bv;
        } else {  // EPI_LOGITS
          ((float*)out)[row * (size_t)N + col] = v + bv;
        }
      }
    }
  }
}

// ---------------- flash attention (causal) ----------------
// q,k: [B*H][T][64] bf16 ; vt: [B*H][64][T] bf16 ; o: [B*T][E] bf16
__global__ __launch_bounds__(256) void attn_kernel(
    const u16* __restrict__ q, const u16* __restrict__ kk,
    const u16* __restrict__ vt, u16* __restrict__ o) {
  __shared__ u16 Qt[64][64], Kt[64][64], Vt[64][64];
  __shared__ u16 P[4][16][64];
  const int qi = blockIdx.x;   // 0..15 (query tile)
  const int bh = blockIdx.y;   // 0..63 (b*H + h)
  const int tid = threadIdx.x, lane = tid & 63, w = tid >> 6;
  const int q0 = qi * 64;
  const int fr = lane & 15;
  const int fc = (lane >> 4) * 8;
  const int srow = lane >> 3;         // staging row within 8
  const int scol = (lane & 7) * 8;    // staging col

  const u16* qb = q + ((size_t)bh * TT + q0) * HSZ;
  {
    const int j0 = w * 2, j1 = w * 2 + 1;
    GLD16(qb + (j0 * 8 + srow) * HSZ + scol, &Qt[j0 * 8][0]);
    GLD16(qb + (j1 * 8 + srow) * HSZ + scol, &Qt[j1 * 8][0]);
  }

  f32x4 O[4] = {};
  float mrun = -3.0e38f, lrun = 0.f;

  for (int ki = 0; ki <= qi; ++ki) {
    const int k0 = ki * 64;
    const u16* kb = kk + ((size_t)bh * TT + k0) * HSZ;
    const u16* vb = vt + (size_t)bh * HSZ * TT + k0;
    __syncthreads();
    {
      const int j0 = w * 2, j1 = w * 2 + 1;
      GLD16(kb + (j0 * 8 + srow) * HSZ + scol, &Kt[j0 * 8][0]);
      GLD16(kb + (j1 * 8 + srow) * HSZ + scol, &Kt[j1 * 8][0]);
      GLD16(vb + (size_t)(j0 * 8 + srow) * TT + scol, &Vt[j0 * 8][0]);
      GLD16(vb + (size_t)(j1 * 8 + srow) * TT + scol, &Vt[j1 * 8][0]);
    }
    asm volatile("s_waitcnt vmcnt(0)" ::: "memory");
    __syncthreads();

    // S^T tile: rows tk (64), cols tq (16 per wave): mfma(K, Q)
    const short8 qf0 = *(const short8*)&Qt[w * 16 + fr][fc];
    const short8 qf1 = *(const short8*)&Qt[w * 16 + fr][fc + 32];
    float sv[4][4];
#pragma unroll
    for (int tb = 0; tb < 4; ++tb) {
      const short8 kf0 = *(const short8*)&Kt[tb * 16 + fr][fc];
      const short8 kf1 = *(const short8*)&Kt[tb * 16 + fr][fc + 32];
      f32x4 sacc = {};
      sacc = __builtin_amdgcn_mfma_f32_16x16x32_bf16(kf0, qf0, sacc, 0, 0, 0);
      sacc = __builtin_amdgcn_mfma_f32_16x16x32_bf16(kf1, qf1, sacc, 0, 0, 0);
#pragma unroll
      for (int f = 0; f < 4; ++f) sv[tb][f] = sacc[f] * 0.125f;
    }
    if (ki == qi) {  // causal mask on diagonal tile
      const int tq = w * 16 + fr;
#pragma unroll
      for (int tb = 0; tb < 4; ++tb)
#pragma unroll
        for (int f = 0; f < 4; ++f) {
          const int tk = tb * 16 + ((lane >> 4) << 2) + f;
          if (tq < tk) sv[tb][f] = -1e9f;
        }
    }
    // online softmax (per tq = w*16 + fr)
    float pm = sv[0][0];
#pragma unroll
    for (int tb = 0; tb < 4; ++tb)
#pragma unroll
      for (int f = 0; f < 4; ++f) pm = fmaxf(pm, sv[tb][f]);
    pm = fmaxf(pm, __shfl_xor(pm, 16));
    pm = fmaxf(pm, __shfl_xor(pm, 32));
    const float mnew = fmaxf(mrun, pm);
    const float alpha = __expf(mrun - mnew);
    float psum = 0.f;
    float pv[4][4];
#pragma unroll
    for (int tb = 0; tb < 4; ++tb)
#pragma unroll
      for (int f = 0; f < 4; ++f) {
        const float e = __expf(sv[tb][f] - mnew);
        pv[tb][f] = e;
        psum += e;
      }
    psum += __shfl_xor(psum, 16);
    psum += __shfl_xor(psum, 32);
    lrun = lrun * alpha + psum;
    mrun = mnew;
    // rescale O (O rows are tq = 4*(lane>>4)+f within the wave's 16)
#pragma unroll
    for (int f = 0; f < 4; ++f) {
      const float af = __shfl(alpha, (lane & 48) | (((lane >> 4) << 2) + f));
      O[0][f] *= af; O[1][f] *= af; O[2][f] *= af; O[3][f] *= af;
    }
    // pack P^T -> per-wave LDS as P[tq][tk] bf16
#pragma unroll
    for (int tb = 0; tb < 4; ++tb) {
      uint2 pk;
      pk.x = (unsigned)f2bf(pv[tb][0]) | ((unsigned)f2bf(pv[tb][1]) << 16);
      pk.y = (unsigned)f2bf(pv[tb][2]) | ((unsigned)f2bf(pv[tb][3]) << 16);
      *(uint2*)&P[w][fr][tb * 16 + ((lane >> 4) << 2)] = pk;
    }
    // O += P * V : A = P[tq][tk], B = Vt[d][tk]
    const short8 pa0 = *(const short8*)&P[w][fr][fc];
    const short8 pa1 = *(const short8*)&P[w][fr][fc + 32];
#pragma unroll
    for (int nb = 0; nb < 4; ++nb) {
      const short8 vf0 = *(const short8*)&Vt[nb * 16 + fr][fc];
      const short8 vf1 = *(const short8*)&Vt[nb * 16 + fr][fc + 32];
      O[nb] = __builtin_amdgcn_mfma_f32_16x16x32_bf16(pa0, vf0, O[nb], 0, 0, 0);
      O[nb] = __builtin_amdgcn_mfma_f32_16x16x32_bf16(pa1, vf1, O[nb], 0, 0, 0);
    }
  }

  // final normalize + store: o[b*T + q0 + tq][h*64 + d]
  const int hcol = (bh & (HHD - 1)) * HSZ;
  const size_t rowbase = (size_t)(bh >> 4) * TT + q0 + w * 16;
#pragma unroll
  for (int f = 0; f < 4; ++f) {
    const float linv = 1.f / __shfl(lrun, (lane & 48) | (((lane >> 4) << 2) + f));
    const size_t row = rowbase + ((lane >> 4) << 2) + f;
#pragma unroll
    for (int nb = 0; nb < 4; ++nb)
      o[row * EE + hcol + nb * 16 + fr] = f2bf(O[nb][f] * linv);
  }
}

// ---------------- loss ----------------
__global__ void loss_zero(float* p) {
  if (threadIdx.x == 0) *p = 0.f;
}

__global__ __launch_bounds__(256) void loss_kernel(
    const float* __restrict__ logits, const int* __restrict__ tgt,
    float* __restrict__ lossp) {
  const int row = blockIdx.x, tid = threadIdx.x;
  const int lane = tid & 63, w = tid >> 6;
  const float* lr = logits + (size_t)row * VVC;
  float mx = -3.0e38f, sum = 0.f;
  for (int i = tid; i < VVC; i += 256) {
    const float v = lr[i];
    const float nm = fmaxf(mx, v);
    sum = sum * __expf(mx - nm) + __expf(v - nm);
    mx = nm;
  }
#pragma unroll
  for (int off = 1; off < 64; off <<= 1) {
    const float m2 = __shfl_xor(mx, off), s2 = __shfl_xor(sum, off);
    const float nm = fmaxf(mx, m2);
    sum = sum * __expf(mx - nm) + s2 * __expf(m2 - nm);
    mx = nm;
  }
  __shared__ float lm[4], ls[4];
  if (lane == 0) { lm[w] = mx; ls[w] = sum; }
  __syncthreads();
  if (tid == 0) {
    float M = lm[0], Sm = ls[0];
#pragma unroll
    for (int i = 1; i < 4; ++i) {
      const float nm = fmaxf(M, lm[i]);
      Sm = Sm * __expf(M - nm) + ls[i] * __expf(lm[i] - nm);
      M = nm;
    }
    const float lse = M + logf(Sm);
    const float loss = lse - lr[tgt[row]];
    atomicAdd(lossp, loss * (1.f / (float)NNR));
  }
}

// ---------------- launcher ----------------
extern "C" void kernel_launch(void* const* d_in, const int* in_sizes, int n_in,
                              void* d_out, int out_size, void* d_ws, size_t ws_size,
                              hipStream_t stream) {
  (void)in_sizes; (void)n_in; (void)out_size; (void)ws_size;
  const int* idx = (const int*)d_in[0];
  const int* targets = (const int*)d_in[1];
  const float* tok_emb = (const float*)d_in[2];
  const float* pos_emb = (const float*)d_in[3];
  const float* Wq = (const float*)d_in[4];
  const float* Wk = (const float*)d_in[5];
  const float* Wv = (const float*)d_in[6];
  const float* Wo = (const float*)d_in[7];
  const float* bo = (const float*)d_in[8];
  const float* ln1_g = (const float*)d_in[9];
  const float* ln1_b = (const float*)d_in[10];
  const float* ln2_g = (const float*)d_in[11];
  const float* ln2_b = (const float*)d_in[12];
  const float* W1 = (const float*)d_in[13];
  const float* b1 = (const float*)d_in[14];
  const float* W2 = (const float*)d_in[15];
  const float* b2 = (const float*)d_in[16];
  const float* lnf_g = (const float*)d_in[17];
  const float* lnf_b = (const float*)d_in[18];
  const float* Wout = (const float*)d_in[19];
  const float* bout = (const float*)d_in[20];

  // ---- workspace layout (reduced footprint, ~143 MB) ----
  char* wp = (char*)d_ws;
  auto alloc = [&](size_t elems, size_t esz) -> void* {
    void* p = (void*)wp;
    wp += (elems * esz + 255) & ~(size_t)255;
    return p;
  };
  // per-layer reusable transposed weights
  u16* wqT = (u16*)alloc((size_t)EE * EE, 2);       // 2 MB
  u16* wkT = (u16*)alloc((size_t)EE * EE, 2);       // 2 MB
  u16* wvT = (u16*)alloc((size_t)EE * EE, 2);       // 2 MB
  u16* woT = (u16*)alloc((size_t)EE * EE, 2);       // 2 MB
  u16* w1T = (u16*)alloc((size_t)EE * FFD, 2);      // 8 MB
  u16* w2T = (u16*)alloc((size_t)EE * FFD, 2);      // 8 MB
  u16* woutT = (u16*)alloc((size_t)VVC * EE, 2);    // 62.5 MB
  float* x = (float*)alloc((size_t)NNR * EE, 4);    // 16 MB
  u16* hbuf = (u16*)alloc((size_t)NNR * EE, 2);     // 8 MB
  // a1buf (32 MB) aliases the qkv/o region (safe by stream ordering)
  u16* qbuf = (u16*)alloc((size_t)NNR * EE, 2);     // 8 MB
  u16* kbuf = (u16*)alloc((size_t)NNR * EE, 2);     // 8 MB
  u16* vtb = (u16*)alloc((size_t)NNR * EE, 2);      // 8 MB
  u16* obuf = (u16*)alloc((size_t)NNR * EE, 2);     // 8 MB
  u16* a1buf = qbuf;                                // [NNR][FFD] alias

  const dim3 blk(256);
  // Wout transpose once per call
  transpose_cvt<<<dim3(VVC / 32, EE / 32), blk, 0, stream>>>(Wout, woutT, EE, VVC);

  embed_kernel<<<NNR, blk, 0, stream>>>(idx, tok_emb, pos_emb, x);

  for (int l = 0; l < LLY; ++l) {
    // per-layer weight transposes into reused buffers
    transpose_cvt<<<dim3(EE / 32, EE / 32), blk, 0, stream>>>(
        Wq + (size_t)l * EE * EE, wqT, EE, EE);
    transpose_cvt<<<dim3(EE / 32, EE / 32), blk, 0, stream>>>(
        Wk + (size_t)l * EE * EE, wkT, EE, EE);
    transpose_cvt<<<dim3(EE / 32, EE / 32), blk, 0, stream>>>(
        Wv + (size_t)l * EE * EE, wvT, EE, EE);
    transpose_cvt<<<dim3(EE / 32, EE / 32), blk, 0, stream>>>(
        Wo + (size_t)l * EE * EE, woT, EE, EE);
    transpose_cvt<<<dim3(FFD / 32, EE / 32), blk, 0, stream>>>(
        W1 + (size_t)l * EE * FFD, w1T, EE, FFD);
    transpose_cvt<<<dim3(EE / 32, FFD / 32), blk, 0, stream>>>(
        W2 + (size_t)l * EE * FFD, w2T, FFD, EE);

    ln_bf16<<<NNR, blk, 0, stream>>>(x, ln1_g + l * EE, ln1_b + l * EE, hbuf);
    gemm_bf16<EPI_QKV><<<dim3(EE / 128, NNR / 128), blk, 0, stream>>>(
        hbuf, wqT, nullptr, qbuf, nullptr, NNR, EE, EE);
    gemm_bf16<EPI_QKV><<<dim3(EE / 128, NNR / 128), blk, 0, stream>>>(
        hbuf, wkT, nullptr, kbuf, nullptr, NNR, EE, EE);
    gemm_bf16<EPI_VT><<<dim3(EE / 128, NNR / 128), blk, 0, stream>>>(
        hbuf, wvT, nullptr, vtb, nullptr, NNR, EE, EE);
    attn_kernel<<<dim3(TT / 64, BBS * HHD), blk, 0, stream>>>(qbuf, kbuf, vtb, obuf);
    gemm_bf16<EPI_RES><<<dim3(EE / 128, NNR / 128), blk, 0, stream>>>(
        obuf, woT, bo + l * EE, nullptr, x, NNR, EE, EE);
    ln_bf16<<<NNR, blk, 0, stream>>>(x, ln2_g + l * EE, ln2_b + l * EE, hbuf);
    gemm_bf16<EPI_BIAS_RELU><<<dim3(FFD / 128, NNR / 128), blk, 0, stream>>>(
        hbuf, w1T, b1 + l * FFD, a1buf, nullptr, NNR, FFD, EE);
    gemm_bf16<EPI_RES><<<dim3(EE / 128, NNR / 128), blk, 0, stream>>>(
        a1buf, w2T, b2 + l * EE, nullptr, x, NNR, EE, FFD);
  }

  ln_bf16<<<NNR, blk, 0, stream>>>(x, lnf_g, lnf_b, hbuf);
  gemm_bf16<EPI_LOGITS><<<dim3(VVC / 128, NNR / 128), blk, 0, stream>>>(
      hbuf, woutT, bout, d_out, nullptr, NNR, VVC, EE);

  float* lossp = (float*)d_out + (size_t)NNR * VVC;
  loss_zero<<<1, 64, 0, stream>>>(lossp);
  loss_kernel<<<NNR, blk, 0, stream>>>((const float*)d_out, targets, lossp);
}